// Round 22
// baseline (266.450 us; speedup 1.0000x reference)
//
#include <hip/hip_runtime.h>
#include <hip/hip_bf16.h>
#include <cstdio>
#include <cstdint>

// MoE MLP fused forward. T=512, K=2, E=32, H=512, I=512 (2I=1024).
//
// SESSION FINDINGS (r0-21), probe-verified on device:
//  * Source compiles fresh (r14), .so loads, kernel_launch runs (r15/r16).
//  * ALL float tensors are FLOAT32 on device (r20/r21: x=1.0078,-0.9062;
//    ew=0.902,0.914; slab sizes match f32). Harness widens bf16<->f32 at the
//    device boundary — INPUTS AND OUTPUT.
//  * The validated output buffer is the FULL 1MB at d_out = 262144 x f32.
//    Prior bf16 (2-byte) writes filled only the lower 512KB: f32 elements
//    >=131072 stayed zero -> the immortal absmax 0.859375 (r0-r16), and
//    upper-half writes were the only probes that moved absmax (r19, r21).
//
// ROUND-22: identical audited compute, output stored as f32 (full buffer).
// Expected: PASS, absmax ~1e-3 vs np/f32 reference.
//
// Kernel: one block per token, 256 threads (4 waves). Per slot s, e=idx[t,s]:
//   Phase A: t1[c] = dot(x[t,:], w1[e,c,:]) (c=0..1023); 16 lanes/column,
//            float2 loads (lanes coalesce 128B), shfl_down(16) reduce.
//   swiglu:  g=min(t1[2p]+b1[2p],7); l=clip(t1[2p+1]+b1[2p+1],-7,7)
//            h[p] = g*sigmoid(1.702*g)*(l+1)
//   Phase B: t2[c] = dot(h, w2[e,c,:]) + b2[e,c]; oa[c] += ew[t,s]*t2[c]
//   out[t,c] = (f32) oa[c]
__global__ void MoEMLPFused_74191265071207_kernel(
    const float* moe_x,    // (512, 512) f32
    const int*   moe_idx,  // (512, 2) int32
    const float* moe_ew,   // (512, 2) f32
    const float* moe_w1,   // (32, 1024, 512) f32
    const float* moe_b1,   // (32, 1024) f32
    const float* moe_w2,   // (32, 512, 512) f32
    const float* moe_b2,   // (32, 512) f32
    float*       moe_out)  // (512, 512) f32 — full 1MB validated buffer
{
    __shared__ float moe_xs[512];    // x row
    __shared__ float moe_ts[1024];   // mlp1 raw dots
    __shared__ float moe_hs[512];    // swiglu output
    __shared__ float moe_oa[512];    // slot-weighted accumulator

    const int moe_t    = blockIdx.x;
    const int moe_tid  = threadIdx.x;   // 0..255
    const int moe_wave = moe_tid >> 6;  // 0..3
    const int moe_lane = moe_tid & 63;  // 0..63
    const int moe_grp  = moe_lane >> 4; // 0..3  concurrent column in wave
    const int moe_m    = moe_lane & 15; // 0..15 k-chunk lane

    moe_xs[moe_tid * 2 + 0] = moe_x[moe_t * 512 + moe_tid * 2 + 0];
    moe_xs[moe_tid * 2 + 1] = moe_x[moe_t * 512 + moe_tid * 2 + 1];
    moe_oa[moe_tid * 2 + 0] = 0.0f;
    moe_oa[moe_tid * 2 + 1] = 0.0f;

    for (int moe_s = 0; moe_s < 2; ++moe_s) {
        int moe_e = moe_idx[moe_t * 2 + moe_s];
        if (moe_e < 0) moe_e = 0;
        if (moe_e > 31) moe_e = 31;
        const float moe_wgt = moe_ew[moe_t * 2 + moe_s];

        // s=0: staging done. s=1: prior slot's hs/ts reads complete.
        __syncthreads();

        // ---- Phase A ----
        for (int moe_cb = 0; moe_cb < 256; moe_cb += 4) {
            const int moe_c = moe_wave * 256 + moe_cb + moe_grp;
            const float2* moe_wrow = (const float2*)(
                moe_w1 + ((size_t)moe_e * 1024 + (size_t)moe_c) * 512);
            float moe_acc = 0.0f;
            for (int moe_jj = 0; moe_jj < 16; ++moe_jj) {
                const int moe_i = moe_m + 16 * moe_jj;   // lanes coalesce 128B
                const float2 moe_f = moe_wrow[moe_i];
                moe_acc += moe_xs[moe_i * 2 + 0] * moe_f.x
                         + moe_xs[moe_i * 2 + 1] * moe_f.y;
            }
            moe_acc += __shfl_down(moe_acc, 8, 16);
            moe_acc += __shfl_down(moe_acc, 4, 16);
            moe_acc += __shfl_down(moe_acc, 2, 16);
            moe_acc += __shfl_down(moe_acc, 1, 16);
            if (moe_m == 0) moe_ts[moe_c] = moe_acc;
        }

        __syncthreads();   // ts ready

        // ---- swiglu: even col = gate, odd col = linear ----
        for (int moe_pp = 0; moe_pp < 2; ++moe_pp) {
            const int moe_p = moe_tid + moe_pp * 256;
            float moe_g = moe_ts[moe_p * 2 + 0] + moe_b1[moe_e * 1024 + moe_p * 2 + 0];
            float moe_l = moe_ts[moe_p * 2 + 1] + moe_b1[moe_e * 1024 + moe_p * 2 + 1];
            if (moe_g > 7.0f) moe_g = 7.0f;
            if (moe_l > 7.0f) moe_l = 7.0f;
            if (moe_l < -7.0f) moe_l = -7.0f;
            const float moe_sig = 1.0f / (1.0f + expf(-1.702f * moe_g));
            moe_hs[moe_p] = moe_g * moe_sig * (moe_l + 1.0f);
        }

        __syncthreads();   // hs ready

        // ---- Phase B ----
        for (int moe_cb = 0; moe_cb < 128; moe_cb += 4) {
            const int moe_c = moe_wave * 128 + moe_cb + moe_grp;
            const float2* moe_wrow = (const float2*)(
                moe_w2 + ((size_t)moe_e * 512 + (size_t)moe_c) * 512);
            float moe_acc = 0.0f;
            for (int moe_jj = 0; moe_jj < 16; ++moe_jj) {
                const int moe_i = moe_m + 16 * moe_jj;
                const float2 moe_f = moe_wrow[moe_i];
                moe_acc += moe_hs[moe_i * 2 + 0] * moe_f.x
                         + moe_hs[moe_i * 2 + 1] * moe_f.y;
            }
            moe_acc += __shfl_down(moe_acc, 8, 16);
            moe_acc += __shfl_down(moe_acc, 4, 16);
            moe_acc += __shfl_down(moe_acc, 2, 16);
            moe_acc += __shfl_down(moe_acc, 1, 16);
            if (moe_m == 0)
                moe_oa[moe_c] += moe_wgt * (moe_acc + moe_b2[moe_e * 512 + moe_c]);
        }
    }

    __syncthreads();   // oa complete
    // F32 output across the full validated buffer (discovery r21/r22).
    moe_out[moe_t * 512 + moe_tid * 2 + 0] = moe_oa[moe_tid * 2 + 0];
    moe_out[moe_t * 512 + moe_tid * 2 + 1] = moe_oa[moe_tid * 2 + 1];
}

extern "C" void kernel_launch(void* const* d_in, const int* in_sizes, int n_in,
                              void* d_out, int out_size, void* d_ws, size_t ws_size,
                              hipStream_t stream) {
    const float* moe_x  = (const float*)d_in[0];
    const int*   moe_idx = (const int*)d_in[1];
    const float* moe_ew = (const float*)d_in[2];
    const float* moe_w1 = (const float*)d_in[3];
    const float* moe_b1 = (const float*)d_in[4];
    const float* moe_w2 = (const float*)d_in[5];
    const float* moe_b2 = (const float*)d_in[6];
    float* moe_out = (float*)d_out;

    hipStreamCaptureStatus moe_cap = hipStreamCaptureStatusNone;
    (void)hipStreamIsCapturing(stream, &moe_cap);

    MoEMLPFused_74191265071207_kernel<<<512, 256, 0, stream>>>(
        moe_x, moe_idx, moe_ew, moe_w1, moe_b1, moe_w2, moe_b2, moe_out);

    if (moe_cap == hipStreamCaptureStatusNone) {
        // Correctness call only: confirm output values land as f32.
        float moe_ov[4] = {0}, moe_uv[4] = {0};
        (void)hipStreamSynchronize(stream);
        (void)hipMemcpyAsync(moe_ov, moe_out, 16, hipMemcpyDeviceToHost, stream);
        (void)hipMemcpyAsync(moe_uv, moe_out + 131072, 16,
                             hipMemcpyDeviceToHost, stream);
        (void)hipStreamSynchronize(stream);
        fprintf(stderr, "MOE22 lo=%.5f,%.5f,%.5f,%.5f hi=%.5f,%.5f,%.5f,%.5f\n",
                moe_ov[0], moe_ov[1], moe_ov[2], moe_ov[3],
                moe_uv[0], moe_uv[1], moe_uv[2], moe_uv[3]);
        fflush(stderr);
    }
}

// Round 23
// 157.542 us; speedup vs baseline: 1.6913x; 1.6913x over previous
//
#include <hip/hip_runtime.h>
#include <hip/hip_bf16.h>
#include <cstdint>

// MoE MLP fused forward. T=512, K=2 slots, E=32, H=512, I=512 (2I=1024).
// DEVICE DTYPES (probe-verified r20-r22): all float tensors are f32 on
// device (harness widens bf16<->f32); output = full 262144 x f32 at d_out.
//
// r22 baseline (per-token blocks): 266 us, 1.0 GB HBM/dispatch @ 42% peak,
// VALUBusy 12%, MfmaUtil 0 -> memory-bound on per-token weight re-reads
// (3 GB logical vs 96 MB unique weights).
// r23: expert-grouped pipeline — route pairs by expert; each block = one
// expert x 64 columns; 32-token x-tile staged in LDS; weight rows held in
// registers across the token loop => weights read ~once (~130 MB total).
// Deterministic: per-pair results are independent of routing list order;
// combine sums slots in fixed order.

#define MOE_T 512
#define MOE_E 32
#define MOE_H 512
#define MOE_I 512
#define MOE_2I 1024
#define MOE_CAP 1024
#define MOE_MT 32   // token tile

// ---------------- route: bucket (token,slot) pairs by expert ----------------
__global__ __launch_bounds__(1024) void moe_route(const int* __restrict__ idx,
                                                  int* __restrict__ cnt,
                                                  int* __restrict__ lists) {
    __shared__ int scnt[MOE_E];
    const int p = threadIdx.x;             // pair id = token*2 + slot
    if (p < MOE_E) scnt[p] = 0;
    __syncthreads();
    int e = idx[p];
    e = (e < 0) ? 0 : (e > MOE_E - 1 ? MOE_E - 1 : e);
    const int pos = atomicAdd(&scnt[e], 1);
    lists[e * MOE_CAP + pos] = p;
    __syncthreads();
    if (p < MOE_E) cnt[p] = scnt[p];
}

// ---- mlp1 + swiglu: grid (2I/64=16, E). Block: expert e, 32 i-pairs. ----
// 16-lane groups each own a (gate,lin) column pair; weight rows in regs;
// token tile in LDS. h[pair][i] written to hbuf (f32).
__global__ __launch_bounds__(256) void moe_mlp1(
    const float* __restrict__ x, const float* __restrict__ w1,
    const float* __restrict__ b1, const int* __restrict__ cnt,
    const int* __restrict__ lists, float* __restrict__ hbuf) {
    __shared__ float xs[MOE_MT][MOE_H];
    const int e = blockIdx.y;
    const int ne = cnt[e];
    if (ne == 0) return;
    const int i0 = blockIdx.x * 32;        // 32 i-pairs (=64 columns)
    const int tid = threadIdx.x;
    const int gid = (tid >> 6) * 4 + ((tid & 63) >> 4);  // 0..15
    const int m16 = tid & 15;
    const int* lst = lists + e * MOE_CAP;

    for (int m0 = 0; m0 < ne; m0 += MOE_MT) {
        __syncthreads();   // prior tile fully consumed
        for (int j = 0; j < MOE_MT; ++j) {
            const int pm = lst[min(m0 + j, ne - 1)];
            ((float2*)xs[j])[tid] =
                ((const float2*)(x + (size_t)(pm >> 1) * MOE_H))[tid];
        }
        __syncthreads();

        for (int r = 0; r < 2; ++r) {
            const int i  = i0 + gid * 2 + r;
            const int cg = 2 * i;
            const float2* wg = (const float2*)(w1 + ((size_t)e * MOE_2I + cg) * MOE_H);
            const float2* wl = (const float2*)(w1 + ((size_t)e * MOE_2I + cg + 1) * MOE_H);
            float2 rg[16], rl[16];
            #pragma unroll
            for (int jj = 0; jj < 16; ++jj) {   // 16 lanes x float2 = 128B coalesced
                rg[jj] = wg[m16 + 16 * jj];
                rl[jj] = wl[m16 + 16 * jj];
            }
            const float bg = b1[e * MOE_2I + cg];
            const float bl = b1[e * MOE_2I + cg + 1];
            const int mend = min(MOE_MT, ne - m0);
            for (int m = 0; m < mend; ++m) {
                float ag = 0.0f, al = 0.0f;
                const float2* xm = (const float2*)xs[m];
                #pragma unroll
                for (int jj = 0; jj < 16; ++jj) {
                    const float2 xv = xm[m16 + 16 * jj];
                    ag += rg[jj].x * xv.x + rg[jj].y * xv.y;
                    al += rl[jj].x * xv.x + rl[jj].y * xv.y;
                }
                ag += __shfl_down(ag, 8, 16); al += __shfl_down(al, 8, 16);
                ag += __shfl_down(ag, 4, 16); al += __shfl_down(al, 4, 16);
                ag += __shfl_down(ag, 2, 16); al += __shfl_down(al, 2, 16);
                ag += __shfl_down(ag, 1, 16); al += __shfl_down(al, 1, 16);
                if (m16 == 0) {
                    float g = ag + bg, l = al + bl;
                    g = fminf(g, 7.0f);
                    l = fminf(fmaxf(l, -7.0f), 7.0f);
                    const float h = g / (1.0f + expf(-1.702f * g)) * (l + 1.0f);
                    hbuf[(size_t)lst[m0 + m] * MOE_I + i] = h;
                }
            }
        }
    }
}

// ---- mlp2: grid (H/64=8, E). Block: expert e, 64 output columns. ----
__global__ __launch_bounds__(256) void moe_mlp2(
    const float* __restrict__ hbuf, const float* __restrict__ w2,
    const float* __restrict__ b2, const int* __restrict__ cnt,
    const int* __restrict__ lists, float* __restrict__ pairout) {
    __shared__ float hs[MOE_MT][MOE_I];
    const int e = blockIdx.y;
    const int ne = cnt[e];
    if (ne == 0) return;
    const int c0 = blockIdx.x * 64;
    const int tid = threadIdx.x;
    const int gid = (tid >> 6) * 4 + ((tid & 63) >> 4);
    const int m16 = tid & 15;
    const int* lst = lists + e * MOE_CAP;

    for (int m0 = 0; m0 < ne; m0 += MOE_MT) {
        __syncthreads();
        for (int j = 0; j < MOE_MT; ++j) {
            const int pm = lst[min(m0 + j, ne - 1)];
            ((float2*)hs[j])[tid] =
                ((const float2*)(hbuf + (size_t)pm * MOE_I))[tid];
        }
        __syncthreads();

        for (int r = 0; r < 4; ++r) {
            const int c = c0 + gid * 4 + r;
            const float2* wr = (const float2*)(w2 + ((size_t)e * MOE_H + c) * MOE_I);
            float2 rw[16];
            #pragma unroll
            for (int jj = 0; jj < 16; ++jj) rw[jj] = wr[m16 + 16 * jj];
            const float bc = b2[e * MOE_H + c];
            const int mend = min(MOE_MT, ne - m0);
            for (int m = 0; m < mend; ++m) {
                float acc = 0.0f;
                const float2* hm = (const float2*)hs[m];
                #pragma unroll
                for (int jj = 0; jj < 16; ++jj) {
                    const float2 hv = hm[m16 + 16 * jj];
                    acc += rw[jj].x * hv.x + rw[jj].y * hv.y;
                }
                acc += __shfl_down(acc, 8, 16);
                acc += __shfl_down(acc, 4, 16);
                acc += __shfl_down(acc, 2, 16);
                acc += __shfl_down(acc, 1, 16);
                if (m16 == 0)
                    pairout[(size_t)lst[m0 + m] * MOE_H + c] = acc + bc;
            }
        }
    }
}

// ---- combine: out[t,c] = ew[t,0]*pairout[2t,c] + ew[t,1]*pairout[2t+1,c] ----
__global__ __launch_bounds__(256) void MoEMLPFused_74191265071207_kernel(
    const float* __restrict__ pairout, const float* __restrict__ ew,
    float* __restrict__ out) {
    const int o = blockIdx.x * 256 + threadIdx.x;   // < 262144
    const int t = o >> 9;
    const int c = o & 511;
    out[o] = ew[2 * t + 0] * pairout[(size_t)(2 * t + 0) * MOE_H + c]
           + ew[2 * t + 1] * pairout[(size_t)(2 * t + 1) * MOE_H + c];
}

extern "C" void kernel_launch(void* const* d_in, const int* in_sizes, int n_in,
                              void* d_out, int out_size, void* d_ws, size_t ws_size,
                              hipStream_t stream) {
    const float* x   = (const float*)d_in[0];
    const int*   idx = (const int*)d_in[1];
    const float* ew  = (const float*)d_in[2];
    const float* w1  = (const float*)d_in[3];
    const float* b1  = (const float*)d_in[4];
    const float* w2  = (const float*)d_in[5];
    const float* b2  = (const float*)d_in[6];
    float* out = (float*)d_out;

    // Workspace: cnt(128B) | lists(128KB) | hbuf(2MB) | pairout(2MB)
    char* ws = (char*)d_ws;
    int* cnt   = (int*)ws;
    int* lists = (int*)(ws + 256);
    float* hbuf    = (float*)(ws + 256 + MOE_E * MOE_CAP * 4);
    float* pairout = hbuf + (size_t)MOE_T * 2 * MOE_I;

    moe_route<<<1, 1024, 0, stream>>>(idx, cnt, lists);
    moe_mlp1<<<dim3(MOE_2I / 64, MOE_E), 256, 0, stream>>>(x, w1, b1, cnt, lists, hbuf);
    moe_mlp2<<<dim3(MOE_H / 64, MOE_E), 256, 0, stream>>>(hbuf, w2, b2, cnt, lists, pairout);
    MoEMLPFused_74191265071207_kernel<<<(MOE_T * MOE_H) / 256, 256, 0, stream>>>(
        pairout, ew, out);
}